// Round 2
// baseline (2049.954 us; speedup 1.0000x reference)
//
#include <hip/hip_runtime.h>
#include <math.h>

#define N_NODES 100000
#define N_EDGES 1000000
#define IN_F 128
#define HID 64
#define OUT_F 64
#define NLAYERS 4
#define ALPHA 0.1f
#define BN_EPS 1e-5f

// ---- workspace layout (bytes), all 16B-aligned ----
static const size_t OFF_CNT      = 0;                       // N*4      = 400000
static const size_t OFF_STATS    = 400000;                  // 512*4    = 2048
static const size_t ZERO_BYTES   = 402048;
static const size_t OFF_DINV     = 402048;                  // N*4
static const size_t OFF_ROWSTART = 802048;                  // (N+1)*4 -> pad 400016
static const size_t OFF_CURSOR   = 1202064;                 // N*4
static const size_t OFF_SORTED   = 1602064;                 // E*4 = 4000000
static const size_t OFF_X0       = 5602064;                 // N*64*4 = 25600000
static const size_t OFF_HA       = 31202064;
static const size_t OFF_HB       = 56802064;                // end = 82402064

__global__ void hist_kernel(const int* __restrict__ row, int* __restrict__ cnt, int e) {
    int i = blockIdx.x * blockDim.x + threadIdx.x;
    if (i < e) atomicAdd(&cnt[row[i]], 1);
}

__global__ void dinv_kernel(const int* __restrict__ cnt, float* __restrict__ dinv, int n) {
    int i = blockIdx.x * blockDim.x + threadIdx.x;
    if (i < n) {
        int d = cnt[i];
        dinv[i] = d > 0 ? rsqrtf((float)d) : 0.0f;
    }
}

// single-block exclusive scan over n counts -> row_start[0..n], cursor copy
__global__ void scan_kernel(const int* __restrict__ cnt, int* __restrict__ rs,
                            int* __restrict__ cur, int n) {
    __shared__ int lds[1024];
    int t = threadIdx.x;
    int chunk = (n + 1023) >> 10;
    int b = t * chunk;
    int e = b + chunk; if (e > n) e = n;
    int s = 0;
#pragma unroll 4
    for (int j = b; j < e; ++j) s += cnt[j];
    lds[t] = s;
    __syncthreads();
    for (int off = 1; off < 1024; off <<= 1) {
        int v = lds[t];
        int add = (t >= off) ? lds[t - off] : 0;
        __syncthreads();
        lds[t] = v + add;
        __syncthreads();
    }
    int excl = (t == 0) ? 0 : lds[t - 1];
    for (int j = b; j < e; ++j) { rs[j] = excl; cur[j] = excl; excl += cnt[j]; }
    if (t == 1023) rs[n] = lds[1023];
}

__global__ void scatter_kernel(const int* __restrict__ edges, int* __restrict__ cur,
                               int* __restrict__ scol, int e) {
    int i = blockIdx.x * blockDim.x + threadIdx.x;
    if (i < e) {
        int r = edges[i];
        int c = edges[e + i];
        int pos = atomicAdd(&cur[r], 1);
        scol[pos] = c;
    }
}

// x0 = relu(x @ W0 + b0)  [N,128]@[128,64]; wave-per-row, W0 column in regs, shfl broadcast
__global__ __launch_bounds__(256, 2) void fc0_kernel(const float* __restrict__ x,
        const float* __restrict__ W0, const float* __restrict__ b0,
        float* __restrict__ out, int n) {
    int wave = threadIdx.x >> 6, lane = threadIdx.x & 63;
    float w[IN_F];
#pragma unroll
    for (int k = 0; k < IN_F; ++k) w[k] = W0[k * HID + lane];
    float bias = b0[lane];
    int nw = gridDim.x * 4;
    for (int r = blockIdx.x * 4 + wave; r < n; r += nw) {
        float xa = x[(size_t)r * IN_F + lane];
        float xb = x[(size_t)r * IN_F + 64 + lane];
        float acc0 = bias, acc1 = 0.f;
#pragma unroll
        for (int k = 0; k < 64; ++k) {
            acc0 += __shfl(xa, k, 64) * w[k];
            acc1 += __shfl(xb, k, 64) * w[64 + k];
        }
        float v = acc0 + acc1;
        out[(size_t)r * HID + lane] = v > 0.f ? v : 0.f;
    }
}

// per layer: s = (1-a)*D^-1/2 A D^-1/2 x + a*x0 ; h = (1-beta)*s + beta*(s@cw);
// write h, accumulate per-channel sum/sumsq.
// 8-wide predicated edge batches for memory-level parallelism.
__global__ __launch_bounds__(256, 4) void layerA_kernel(const float* __restrict__ xcur,
        const float* __restrict__ x0, const float* __restrict__ dinv,
        const int* __restrict__ rs, const int* __restrict__ scol,
        const float* __restrict__ cw, float* __restrict__ h,
        float* __restrict__ stats, float beta, int n) {
    int wave = threadIdx.x >> 6, lane = threadIdx.x & 63;
    float w[HID];
#pragma unroll
    for (int k = 0; k < HID; ++k) w[k] = cw[k * HID + lane];
    float lsum = 0.f, lsq = 0.f;
    int nw = gridDim.x * 4;
    for (int r = blockIdx.x * 4 + wave; r < n; r += nw) {
        int e0 = rs[r], e1 = rs[r + 1];
        float agg = 0.f;
        for (int e = e0; e < e1; e += 8) {
            int   cc[8];
            float dd[8];
            float vv[8];
#pragma unroll
            for (int j = 0; j < 8; ++j) {
                int ee = e + j;
                int idx = ee < e1 ? ee : e1 - 1;
                cc[j] = scol[idx];
            }
#pragma unroll
            for (int j = 0; j < 8; ++j) {
                dd[j] = (e + j < e1) ? dinv[cc[j]] : 0.f;
                vv[j] = xcur[(size_t)cc[j] * HID + lane];
            }
            float p0 = dd[0] * vv[0] + dd[1] * vv[1];
            float p1 = dd[2] * vv[2] + dd[3] * vv[3];
            float p2 = dd[4] * vv[4] + dd[5] * vv[5];
            float p3 = dd[6] * vv[6] + dd[7] * vv[7];
            agg += (p0 + p1) + (p2 + p3);
        }
        float s = (1.f - ALPHA) * dinv[r] * agg + ALPHA * x0[(size_t)r * HID + lane];
        float m = 0.f;
#pragma unroll
        for (int k = 0; k < HID; ++k) m += __shfl(s, k, 64) * w[k];
        float hv = (1.f - beta) * s + beta * m;
        h[(size_t)r * HID + lane] = hv;
        lsum += hv; lsq += hv * hv;
    }
    atomicAdd(&stats[lane], lsum);
    atomicAdd(&stats[64 + lane], lsq);
}

// BN(train, biased var) + residual + relu, in place on h; float4 vectorized
__global__ void layerB_kernel(float4* __restrict__ h, const float4* __restrict__ xprev,
        const float* __restrict__ stats, const float* __restrict__ gamma,
        const float* __restrict__ bnb, int total4) {
    int i = blockIdx.x * blockDim.x + threadIdx.x;
    if (i >= total4) return;
    int fb = (i & 15) * 4;   // 16 float4 per 64-channel row
    float4 hv = h[i];
    float4 xp = xprev[i];
    float o[4];
    float hin[4] = { hv.x, hv.y, hv.z, hv.w };
    float xin[4] = { xp.x, xp.y, xp.z, xp.w };
#pragma unroll
    for (int j = 0; j < 4; ++j) {
        int f = fb + j;
        float mu = stats[f] * (1.0f / N_NODES);
        float var = stats[64 + f] * (1.0f / N_NODES) - mu * mu;
        if (var < 0.f) var = 0.f;
        float inv = rsqrtf(var + BN_EPS);
        float v = (hin[j] - mu) * inv * gamma[f] + bnb[f] + xin[j];
        o[j] = v > 0.f ? v : 0.f;
    }
    h[i] = make_float4(o[0], o[1], o[2], o[3]);
}

// out = x @ W1 + b1  [N,64]@[64,64]
__global__ __launch_bounds__(256, 4) void final_kernel(const float* __restrict__ xcur,
        const float* __restrict__ W1, const float* __restrict__ b1,
        float* __restrict__ out, int n) {
    int wave = threadIdx.x >> 6, lane = threadIdx.x & 63;
    float w[HID];
#pragma unroll
    for (int k = 0; k < HID; ++k) w[k] = W1[k * OUT_F + lane];
    float bias = b1[lane];
    int nw = gridDim.x * 4;
    for (int r = blockIdx.x * 4 + wave; r < n; r += nw) {
        float xv = xcur[(size_t)r * HID + lane];
        float acc = bias;
#pragma unroll
        for (int k = 0; k < HID; ++k) acc += __shfl(xv, k, 64) * w[k];
        out[(size_t)r * OUT_F + lane] = acc;
    }
}

extern "C" void kernel_launch(void* const* d_in, const int* in_sizes, int n_in,
                              void* d_out, int out_size, void* d_ws, size_t ws_size,
                              hipStream_t stream) {
    const float* x     = (const float*)d_in[0];
    const int*   edges = (const int*)d_in[1];
    const float* W0    = (const float*)d_in[2];
    const float* b0    = (const float*)d_in[3];
    const float* cw    = (const float*)d_in[4];
    const float* gamma = (const float*)d_in[5];
    const float* bnb   = (const float*)d_in[6];
    const float* W1    = (const float*)d_in[7];
    const float* b1    = (const float*)d_in[8];
    float* out = (float*)d_out;

    char* ws = (char*)d_ws;
    int*   cnt   = (int*)(ws + OFF_CNT);
    float* stats = (float*)(ws + OFF_STATS);
    float* dinv  = (float*)(ws + OFF_DINV);
    int*   rs    = (int*)(ws + OFF_ROWSTART);
    int*   cur   = (int*)(ws + OFF_CURSOR);
    int*   scol  = (int*)(ws + OFF_SORTED);
    float* x0    = (float*)(ws + OFF_X0);
    float* bufA  = (float*)(ws + OFF_HA);
    float* bufB  = (float*)(ws + OFF_HB);

    hipMemsetAsync(ws, 0, ZERO_BYTES, stream);
    hist_kernel<<<(N_EDGES + 255) / 256, 256, 0, stream>>>(edges, cnt, N_EDGES);
    dinv_kernel<<<(N_NODES + 255) / 256, 256, 0, stream>>>(cnt, dinv, N_NODES);
    scan_kernel<<<1, 1024, 0, stream>>>(cnt, rs, cur, N_NODES);
    scatter_kernel<<<(N_EDGES + 255) / 256, 256, 0, stream>>>(edges, cur, scol, N_EDGES);
    fc0_kernel<<<3072, 256, 0, stream>>>(x, W0, b0, x0, N_NODES);

    const float* xc = x0;        // current layer input (also residual source)
    float* bufs[2] = { bufA, bufB };
    for (int i = 0; i < NLAYERS; ++i) {
        float beta = logf(0.5f / (float)(i + 1) + 1.0f);
        float* hb = bufs[i & 1];
        layerA_kernel<<<3072, 256, 0, stream>>>(xc, x0, dinv, rs, scol,
                cw + (size_t)i * HID * HID, hb, stats + i * 128, beta, N_NODES);
        layerB_kernel<<<(N_NODES * HID / 4 + 255) / 256, 256, 0, stream>>>(
                (float4*)hb, (const float4*)xc,
                stats + i * 128, gamma + i * HID, bnb + i * HID, N_NODES * HID / 4);
        xc = hb;
    }
    final_kernel<<<3072, 256, 0, stream>>>(xc, W1, b1, out, N_NODES);
}

// Round 3
// 1189.922 us; speedup vs baseline: 1.7228x; 1.7228x over previous
//
#include <hip/hip_runtime.h>
#include <math.h>

#define N_NODES 100000
#define N_EDGES 1000000
#define IN_F 128
#define HID 64
#define OUT_F 64
#define NLAYERS 4
#define ALPHA 0.1f
#define BN_EPS 1e-5f

// ---- workspace layout (bytes) ----
// Feature buffers FIRST so rows are 256B-aligned (a 64-float row = exactly
// two 128B cache lines; the old 16B-offset layout made every gather touch 3).
static const size_t OFF_X0       = 0;                       // N*64*4 = 25600000
static const size_t OFF_HA       = 25600000;                // 25600000
static const size_t OFF_HB       = 51200000;                // 25600000
static const size_t OFF_SORTED   = 76800000;                // E*4 = 4000000
static const size_t OFF_CNT      = 80800000;                // N*4 = 400000
static const size_t OFF_STATS    = 81200000;                // 512*4 = 2048
static const size_t OFF_DINV     = 81202048;                // N*4
static const size_t OFF_ROWSTART = 81602048;                // (N+1)*4 -> 400016
static const size_t OFF_CURSOR   = 82002064;                // N*4 ; end = 82402064
static const size_t ZERO_OFF     = OFF_CNT;                 // cnt+stats contiguous
static const size_t ZERO_BYTES   = 402048;

__global__ void hist_kernel(const int* __restrict__ row, int* __restrict__ cnt, int e) {
    int i = blockIdx.x * blockDim.x + threadIdx.x;
    if (i < e) atomicAdd(&cnt[row[i]], 1);
}

__global__ void dinv_kernel(const int* __restrict__ cnt, float* __restrict__ dinv, int n) {
    int i = blockIdx.x * blockDim.x + threadIdx.x;
    if (i < n) {
        int d = cnt[i];
        dinv[i] = d > 0 ? rsqrtf((float)d) : 0.0f;
    }
}

// single-block exclusive scan over n counts -> row_start[0..n], cursor copy
__global__ void scan_kernel(const int* __restrict__ cnt, int* __restrict__ rs,
                            int* __restrict__ cur, int n) {
    __shared__ int lds[1024];
    int t = threadIdx.x;
    int chunk = (n + 1023) >> 10;
    int b = t * chunk;
    int e = b + chunk; if (e > n) e = n;
    int s = 0;
#pragma unroll 4
    for (int j = b; j < e; ++j) s += cnt[j];
    lds[t] = s;
    __syncthreads();
    for (int off = 1; off < 1024; off <<= 1) {
        int v = lds[t];
        int add = (t >= off) ? lds[t - off] : 0;
        __syncthreads();
        lds[t] = v + add;
        __syncthreads();
    }
    int excl = (t == 0) ? 0 : lds[t - 1];
    for (int j = b; j < e; ++j) { rs[j] = excl; cur[j] = excl; excl += cnt[j]; }
    if (t == 1023) rs[n] = lds[1023];
}

__global__ void scatter_kernel(const int* __restrict__ edges, int* __restrict__ cur,
                               int* __restrict__ scol, int e) {
    int i = blockIdx.x * blockDim.x + threadIdx.x;
    if (i < e) {
        int r = edges[i];
        int c = edges[e + i];
        int pos = atomicAdd(&cur[r], 1);
        scol[pos] = c;
    }
}

// x0 = relu(x @ W0 + b0); wave-per-row, W0 columns in regs ((256,2) => 256 VGPR budget)
__global__ __launch_bounds__(256, 2) void fc0_kernel(const float* __restrict__ x,
        const float* __restrict__ W0, const float* __restrict__ b0,
        float* __restrict__ out, int n) {
    int wave = threadIdx.x >> 6, lane = threadIdx.x & 63;
    float w[IN_F];
#pragma unroll
    for (int k = 0; k < IN_F; ++k) w[k] = W0[k * HID + lane];
    float bias = b0[lane];
    int nw = gridDim.x * 4;
    for (int r = blockIdx.x * 4 + wave; r < n; r += nw) {
        float xa = x[(size_t)r * IN_F + lane];
        float xb = x[(size_t)r * IN_F + 64 + lane];
        float acc0 = bias, acc1 = 0.f;
#pragma unroll
        for (int k = 0; k < 64; ++k) {
            acc0 += __shfl(xa, k, 64) * w[k];
            acc1 += __shfl(xb, k, 64) * w[64 + k];
        }
        float v = acc0 + acc1;
        out[(size_t)r * HID + lane] = v > 0.f ? v : 0.f;
    }
}

// Lean gather-only SPMM: s = (1-a)*dinv[r]*sum(dinv[c]*x[c]) + a*x0[r].
// Batch-4 + exact tail (no wasted gathers), no weight array -> low VGPR, 8 waves/EU.
__global__ __launch_bounds__(256, 8) void spmm_kernel(const float* __restrict__ xcur,
        const float* __restrict__ x0, const float* __restrict__ dinv,
        const int* __restrict__ rs, const int* __restrict__ scol,
        float* __restrict__ sout, int n) {
    int wave = threadIdx.x >> 6, lane = threadIdx.x & 63;
    int nw = gridDim.x * 4;
    for (int r = blockIdx.x * 4 + wave; r < n; r += nw) {
        int e0 = rs[r], e1 = rs[r + 1];
        float agg = 0.f;
        int e = e0;
        for (; e + 4 <= e1; e += 4) {
            int c0 = scol[e], c1 = scol[e + 1], c2 = scol[e + 2], c3 = scol[e + 3];
            float d0 = dinv[c0], d1 = dinv[c1], d2 = dinv[c2], d3 = dinv[c3];
            float v0 = xcur[(size_t)c0 * HID + lane];
            float v1 = xcur[(size_t)c1 * HID + lane];
            float v2 = xcur[(size_t)c2 * HID + lane];
            float v3 = xcur[(size_t)c3 * HID + lane];
            agg += (d0 * v0 + d1 * v1) + (d2 * v2 + d3 * v3);
        }
        for (; e < e1; ++e) {
            int c = scol[e];
            agg += dinv[c] * xcur[(size_t)c * HID + lane];
        }
        sout[(size_t)r * HID + lane] =
            (1.f - ALPHA) * dinv[r] * agg + ALPHA * x0[(size_t)r * HID + lane];
    }
}

// h = (1-beta)*s + beta*(s@cw), in place; per-channel sum/sumsq with block reduce.
// (256,2) guarantees the 64-entry weight column array stays in registers.
__global__ __launch_bounds__(256, 2) void dense_stats_kernel(float* __restrict__ s_in,
        const float* __restrict__ cw, float* __restrict__ stats, float beta, int n) {
    __shared__ float red[4 * 128];
    int wave = threadIdx.x >> 6, lane = threadIdx.x & 63;
    float w[HID];
#pragma unroll
    for (int k = 0; k < HID; ++k) w[k] = cw[k * HID + lane];
    float lsum = 0.f, lsq = 0.f;
    int nw = gridDim.x * 4;
    for (int r = blockIdx.x * 4 + wave; r < n; r += nw) {
        float sv = s_in[(size_t)r * HID + lane];
        float m = 0.f;
#pragma unroll
        for (int k = 0; k < HID; ++k) m += __shfl(sv, k, 64) * w[k];
        float hv = (1.f - beta) * sv + beta * m;
        s_in[(size_t)r * HID + lane] = hv;
        lsum += hv; lsq += hv * hv;
    }
    red[wave * 128 + lane] = lsum;
    red[wave * 128 + 64 + lane] = lsq;
    __syncthreads();
    if (threadIdx.x < 128) {
        int t = threadIdx.x;
        float v = red[t] + red[128 + t] + red[256 + t] + red[384 + t];
        atomicAdd(&stats[t], v);
    }
}

// BN(train, biased var) + residual + relu, in place on h; float4 vectorized
__global__ void layerB_kernel(float4* __restrict__ h, const float4* __restrict__ xprev,
        const float* __restrict__ stats, const float* __restrict__ gamma,
        const float* __restrict__ bnb, int total4) {
    int i = blockIdx.x * blockDim.x + threadIdx.x;
    if (i >= total4) return;
    int fb = (i & 15) * 4;
    float4 hv = h[i];
    float4 xp = xprev[i];
    float o[4];
    float hin[4] = { hv.x, hv.y, hv.z, hv.w };
    float xin[4] = { xp.x, xp.y, xp.z, xp.w };
#pragma unroll
    for (int j = 0; j < 4; ++j) {
        int f = fb + j;
        float mu = stats[f] * (1.0f / N_NODES);
        float var = stats[64 + f] * (1.0f / N_NODES) - mu * mu;
        if (var < 0.f) var = 0.f;
        float inv = rsqrtf(var + BN_EPS);
        float v = (hin[j] - mu) * inv * gamma[f] + bnb[f] + xin[j];
        o[j] = v > 0.f ? v : 0.f;
    }
    h[i] = make_float4(o[0], o[1], o[2], o[3]);
}

// out = x @ W1 + b1
__global__ __launch_bounds__(256, 2) void final_kernel(const float* __restrict__ xcur,
        const float* __restrict__ W1, const float* __restrict__ b1,
        float* __restrict__ out, int n) {
    int wave = threadIdx.x >> 6, lane = threadIdx.x & 63;
    float w[HID];
#pragma unroll
    for (int k = 0; k < HID; ++k) w[k] = W1[k * OUT_F + lane];
    float bias = b1[lane];
    int nw = gridDim.x * 4;
    for (int r = blockIdx.x * 4 + wave; r < n; r += nw) {
        float xv = xcur[(size_t)r * HID + lane];
        float acc = bias;
#pragma unroll
        for (int k = 0; k < HID; ++k) acc += __shfl(xv, k, 64) * w[k];
        out[(size_t)r * OUT_F + lane] = acc;
    }
}

extern "C" void kernel_launch(void* const* d_in, const int* in_sizes, int n_in,
                              void* d_out, int out_size, void* d_ws, size_t ws_size,
                              hipStream_t stream) {
    const float* x     = (const float*)d_in[0];
    const int*   edges = (const int*)d_in[1];
    const float* W0    = (const float*)d_in[2];
    const float* b0    = (const float*)d_in[3];
    const float* cw    = (const float*)d_in[4];
    const float* gamma = (const float*)d_in[5];
    const float* bnb   = (const float*)d_in[6];
    const float* W1    = (const float*)d_in[7];
    const float* b1    = (const float*)d_in[8];
    float* out = (float*)d_out;

    char* ws = (char*)d_ws;
    float* x0    = (float*)(ws + OFF_X0);
    float* bufA  = (float*)(ws + OFF_HA);
    float* bufB  = (float*)(ws + OFF_HB);
    int*   scol  = (int*)(ws + OFF_SORTED);
    int*   cnt   = (int*)(ws + OFF_CNT);
    float* stats = (float*)(ws + OFF_STATS);
    float* dinv  = (float*)(ws + OFF_DINV);
    int*   rs    = (int*)(ws + OFF_ROWSTART);
    int*   cur   = (int*)(ws + OFF_CURSOR);

    hipMemsetAsync(ws + ZERO_OFF, 0, ZERO_BYTES, stream);
    hist_kernel<<<(N_EDGES + 255) / 256, 256, 0, stream>>>(edges, cnt, N_EDGES);
    dinv_kernel<<<(N_NODES + 255) / 256, 256, 0, stream>>>(cnt, dinv, N_NODES);
    scan_kernel<<<1, 1024, 0, stream>>>(cnt, rs, cur, N_NODES);
    scatter_kernel<<<(N_EDGES + 255) / 256, 256, 0, stream>>>(edges, cur, scol, N_EDGES);
    fc0_kernel<<<2048, 256, 0, stream>>>(x, W0, b0, x0, N_NODES);

    const float* xc = x0;
    float* bufs[2] = { bufA, bufB };
    for (int i = 0; i < NLAYERS; ++i) {
        float beta = logf(0.5f / (float)(i + 1) + 1.0f);
        float* hb = bufs[i & 1];
        spmm_kernel<<<2048, 256, 0, stream>>>(xc, x0, dinv, rs, scol, hb, N_NODES);
        dense_stats_kernel<<<1024, 256, 0, stream>>>(hb,
                cw + (size_t)i * HID * HID, stats + i * 128, beta, N_NODES);
        layerB_kernel<<<(N_NODES * HID / 4 + 255) / 256, 256, 0, stream>>>(
                (float4*)hb, (const float4*)xc,
                stats + i * 128, gamma + i * HID, bnb + i * HID, N_NODES * HID / 4);
        xc = hb;
    }
    final_kernel<<<2048, 256, 0, stream>>>(xc, W1, b1, out, N_NODES);
}

// Round 4
// 988.312 us; speedup vs baseline: 2.0742x; 1.2040x over previous
//
#include <hip/hip_runtime.h>
#include <math.h>

#define N_NODES 100000
#define N_EDGES 1000000
#define IN_F 128
#define HID 64
#define OUT_F 64
#define NLAYERS 4
#define ALPHA 0.1f
#define BN_EPS 1e-5f

#define SCAN_BLK 256
#define NSCAN_BLOCKS ((N_NODES + SCAN_BLK - 1) / SCAN_BLK)   // 391

// ---- workspace layout (bytes) ----
// Feature buffers FIRST so rows are 256B-aligned (a 64-float row = exactly
// two 128B cache lines).
static const size_t OFF_X0       = 0;                       // N*64*4 = 25600000
static const size_t OFF_HA       = 25600000;                // 25600000
static const size_t OFF_HB       = 51200000;                // 25600000
static const size_t OFF_SORTED   = 76800000;                // E*4 = 4000000
static const size_t OFF_CNT      = 80800000;                // N*4 = 400000
static const size_t OFF_STATS    = 81200000;                // 512*4 = 2048
static const size_t OFF_DINV     = 81202048;                // N*4
static const size_t OFF_ROWSTART = 81602048;                // (N+1)*4 -> 400016
static const size_t OFF_CURSOR   = 82002064;                // N*4
static const size_t OFF_BSUM     = 82402064;                // 391*4 -> pad 2048
static const size_t ZERO_OFF     = OFF_CNT;                 // cnt+stats contiguous
static const size_t ZERO_BYTES   = 402048;                  // end = 82404112

__global__ void hist_kernel(const int* __restrict__ row, int* __restrict__ cnt, int e) {
    int i = blockIdx.x * blockDim.x + threadIdx.x;
    if (i < e) atomicAdd(&cnt[row[i]], 1);
}

__global__ void dinv_kernel(const int* __restrict__ cnt, float* __restrict__ dinv, int n) {
    int i = blockIdx.x * blockDim.x + threadIdx.x;
    if (i < n) {
        int d = cnt[i];
        dinv[i] = d > 0 ? rsqrtf((float)d) : 0.0f;
    }
}

// ---- 3-phase multi-block exclusive scan of cnt -> rs[0..n], cur ----
__global__ __launch_bounds__(SCAN_BLK) void blocksum_kernel(const int* __restrict__ cnt,
        int* __restrict__ bsum, int n) {
    __shared__ int red[SCAN_BLK / 64];
    int i = blockIdx.x * SCAN_BLK + threadIdx.x;
    int v = (i < n) ? cnt[i] : 0;
#pragma unroll
    for (int off = 32; off > 0; off >>= 1) v += __shfl_down(v, off, 64);
    if ((threadIdx.x & 63) == 0) red[threadIdx.x >> 6] = v;
    __syncthreads();
    if (threadIdx.x == 0) {
        int s = 0;
#pragma unroll
        for (int j = 0; j < SCAN_BLK / 64; ++j) s += red[j];
        bsum[blockIdx.x] = s;
    }
}

// single block scans NSCAN_BLOCKS block sums (exclusive), in place
__global__ __launch_bounds__(512) void scan_bsum_kernel(int* __restrict__ bsum, int nb) {
    __shared__ int lds[512];
    int t = threadIdx.x;
    lds[t] = (t < nb) ? bsum[t] : 0;
    __syncthreads();
    for (int off = 1; off < 512; off <<= 1) {
        int v = lds[t];
        int add = (t >= off) ? lds[t - off] : 0;
        __syncthreads();
        lds[t] = v + add;
        __syncthreads();
    }
    if (t < nb) bsum[t] = (t == 0) ? 0 : lds[t - 1];
}

__global__ __launch_bounds__(SCAN_BLK) void scan_write_kernel(const int* __restrict__ cnt,
        const int* __restrict__ bsum, int* __restrict__ rs, int* __restrict__ cur, int n) {
    __shared__ int lds[SCAN_BLK];
    int t = threadIdx.x;
    int i = blockIdx.x * SCAN_BLK + t;
    int c = (i < n) ? cnt[i] : 0;
    lds[t] = c;
    __syncthreads();
    for (int off = 1; off < SCAN_BLK; off <<= 1) {
        int v = lds[t];
        int add = (t >= off) ? lds[t - off] : 0;
        __syncthreads();
        lds[t] = v + add;
        __syncthreads();
    }
    if (i < n) {
        int excl = bsum[blockIdx.x] + lds[t] - c;   // inclusive - self = exclusive
        rs[i] = excl;
        cur[i] = excl;
        if (i == n - 1) rs[n] = excl + c;
    }
}

__global__ void scatter_kernel(const int* __restrict__ edges, int* __restrict__ cur,
                               int* __restrict__ scol, int e) {
    int i = blockIdx.x * blockDim.x + threadIdx.x;
    if (i < e) {
        int r = edges[i];
        int c = edges[e + i];
        int pos = atomicAdd(&cur[r], 1);
        scol[pos] = c;
    }
}

// x0 = relu(x @ W0 + b0); wave-per-row, W0 columns in regs ((256,2) => 256 VGPR budget)
__global__ __launch_bounds__(256, 2) void fc0_kernel(const float* __restrict__ x,
        const float* __restrict__ W0, const float* __restrict__ b0,
        float* __restrict__ out, int n) {
    int wave = threadIdx.x >> 6, lane = threadIdx.x & 63;
    float w[IN_F];
#pragma unroll
    for (int k = 0; k < IN_F; ++k) w[k] = W0[k * HID + lane];
    float bias = b0[lane];
    int nw = gridDim.x * 4;
    for (int r = blockIdx.x * 4 + wave; r < n; r += nw) {
        float xa = x[(size_t)r * IN_F + lane];
        float xb = x[(size_t)r * IN_F + 64 + lane];
        float acc0 = bias, acc1 = 0.f;
#pragma unroll
        for (int k = 0; k < 64; ++k) {
            acc0 += __shfl(xa, k, 64) * w[k];
            acc1 += __shfl(xb, k, 64) * w[64 + k];
        }
        float v = acc0 + acc1;
        out[(size_t)r * HID + lane] = v > 0.f ? v : 0.f;
    }
}

// Lean gather-only SPMM: s = (1-a)*dinv[r]*sum(dinv[c]*x[c]) + a*x0[r].
__global__ __launch_bounds__(256, 8) void spmm_kernel(const float* __restrict__ xcur,
        const float* __restrict__ x0, const float* __restrict__ dinv,
        const int* __restrict__ rs, const int* __restrict__ scol,
        float* __restrict__ sout, int n) {
    int wave = threadIdx.x >> 6, lane = threadIdx.x & 63;
    int nw = gridDim.x * 4;
    for (int r = blockIdx.x * 4 + wave; r < n; r += nw) {
        int e0 = rs[r], e1 = rs[r + 1];
        float agg = 0.f;
        int e = e0;
        for (; e + 4 <= e1; e += 4) {
            int c0 = scol[e], c1 = scol[e + 1], c2 = scol[e + 2], c3 = scol[e + 3];
            float d0 = dinv[c0], d1 = dinv[c1], d2 = dinv[c2], d3 = dinv[c3];
            float v0 = xcur[(size_t)c0 * HID + lane];
            float v1 = xcur[(size_t)c1 * HID + lane];
            float v2 = xcur[(size_t)c2 * HID + lane];
            float v3 = xcur[(size_t)c3 * HID + lane];
            agg += (d0 * v0 + d1 * v1) + (d2 * v2 + d3 * v3);
        }
        for (; e < e1; ++e) {
            int c = scol[e];
            agg += dinv[c] * xcur[(size_t)c * HID + lane];
        }
        sout[(size_t)r * HID + lane] =
            (1.f - ALPHA) * dinv[r] * agg + ALPHA * x0[(size_t)r * HID + lane];
    }
}

// h = (1-beta)*s + beta*(s@cw), in place; per-channel sum/sumsq with block reduce.
__global__ __launch_bounds__(256, 2) void dense_stats_kernel(float* __restrict__ s_in,
        const float* __restrict__ cw, float* __restrict__ stats, float beta, int n) {
    __shared__ float red[4 * 128];
    int wave = threadIdx.x >> 6, lane = threadIdx.x & 63;
    float w[HID];
#pragma unroll
    for (int k = 0; k < HID; ++k) w[k] = cw[k * HID + lane];
    float lsum = 0.f, lsq = 0.f;
    int nw = gridDim.x * 4;
    for (int r = blockIdx.x * 4 + wave; r < n; r += nw) {
        float sv = s_in[(size_t)r * HID + lane];
        float m = 0.f;
#pragma unroll
        for (int k = 0; k < HID; ++k) m += __shfl(sv, k, 64) * w[k];
        float hv = (1.f - beta) * sv + beta * m;
        s_in[(size_t)r * HID + lane] = hv;
        lsum += hv; lsq += hv * hv;
    }
    red[wave * 128 + lane] = lsum;
    red[wave * 128 + 64 + lane] = lsq;
    __syncthreads();
    if (threadIdx.x < 128) {
        int t = threadIdx.x;
        float v = red[t] + red[128 + t] + red[256 + t] + red[384 + t];
        atomicAdd(&stats[t], v);
    }
}

// BN(train, biased var) + residual + relu, in place on h; float4 vectorized
__global__ void layerB_kernel(float4* __restrict__ h, const float4* __restrict__ xprev,
        const float* __restrict__ stats, const float* __restrict__ gamma,
        const float* __restrict__ bnb, int total4) {
    int i = blockIdx.x * blockDim.x + threadIdx.x;
    if (i >= total4) return;
    int fb = (i & 15) * 4;
    float4 hv = h[i];
    float4 xp = xprev[i];
    float o[4];
    float hin[4] = { hv.x, hv.y, hv.z, hv.w };
    float xin[4] = { xp.x, xp.y, xp.z, xp.w };
#pragma unroll
    for (int j = 0; j < 4; ++j) {
        int f = fb + j;
        float mu = stats[f] * (1.0f / N_NODES);
        float var = stats[64 + f] * (1.0f / N_NODES) - mu * mu;
        if (var < 0.f) var = 0.f;
        float inv = rsqrtf(var + BN_EPS);
        float v = (hin[j] - mu) * inv * gamma[f] + bnb[f] + xin[j];
        o[j] = v > 0.f ? v : 0.f;
    }
    h[i] = make_float4(o[0], o[1], o[2], o[3]);
}

// out = x @ W1 + b1
__global__ __launch_bounds__(256, 2) void final_kernel(const float* __restrict__ xcur,
        const float* __restrict__ W1, const float* __restrict__ b1,
        float* __restrict__ out, int n) {
    int wave = threadIdx.x >> 6, lane = threadIdx.x & 63;
    float w[HID];
#pragma unroll
    for (int k = 0; k < HID; ++k) w[k] = W1[k * OUT_F + lane];
    float bias = b1[lane];
    int nw = gridDim.x * 4;
    for (int r = blockIdx.x * 4 + wave; r < n; r += nw) {
        float xv = xcur[(size_t)r * HID + lane];
        float acc = bias;
#pragma unroll
        for (int k = 0; k < HID; ++k) acc += __shfl(xv, k, 64) * w[k];
        out[(size_t)r * OUT_F + lane] = acc;
    }
}

extern "C" void kernel_launch(void* const* d_in, const int* in_sizes, int n_in,
                              void* d_out, int out_size, void* d_ws, size_t ws_size,
                              hipStream_t stream) {
    const float* x     = (const float*)d_in[0];
    const int*   edges = (const int*)d_in[1];
    const float* W0    = (const float*)d_in[2];
    const float* b0    = (const float*)d_in[3];
    const float* cw    = (const float*)d_in[4];
    const float* gamma = (const float*)d_in[5];
    const float* bnb   = (const float*)d_in[6];
    const float* W1    = (const float*)d_in[7];
    const float* b1    = (const float*)d_in[8];
    float* out = (float*)d_out;

    char* ws = (char*)d_ws;
    float* x0    = (float*)(ws + OFF_X0);
    float* bufA  = (float*)(ws + OFF_HA);
    float* bufB  = (float*)(ws + OFF_HB);
    int*   scol  = (int*)(ws + OFF_SORTED);
    int*   cnt   = (int*)(ws + OFF_CNT);
    float* stats = (float*)(ws + OFF_STATS);
    float* dinv  = (float*)(ws + OFF_DINV);
    int*   rs    = (int*)(ws + OFF_ROWSTART);
    int*   cur   = (int*)(ws + OFF_CURSOR);
    int*   bsum  = (int*)(ws + OFF_BSUM);

    hipMemsetAsync(ws + ZERO_OFF, 0, ZERO_BYTES, stream);
    hist_kernel<<<(N_EDGES + 255) / 256, 256, 0, stream>>>(edges, cnt, N_EDGES);
    dinv_kernel<<<(N_NODES + 255) / 256, 256, 0, stream>>>(cnt, dinv, N_NODES);
    blocksum_kernel<<<NSCAN_BLOCKS, SCAN_BLK, 0, stream>>>(cnt, bsum, N_NODES);
    scan_bsum_kernel<<<1, 512, 0, stream>>>(bsum, NSCAN_BLOCKS);
    scan_write_kernel<<<NSCAN_BLOCKS, SCAN_BLK, 0, stream>>>(cnt, bsum, rs, cur, N_NODES);
    scatter_kernel<<<(N_EDGES + 255) / 256, 256, 0, stream>>>(edges, cur, scol, N_EDGES);
    fc0_kernel<<<2048, 256, 0, stream>>>(x, W0, b0, x0, N_NODES);

    const float* xc = x0;
    float* bufs[2] = { bufA, bufB };
    for (int i = 0; i < NLAYERS; ++i) {
        float beta = logf(0.5f / (float)(i + 1) + 1.0f);
        float* hb = bufs[i & 1];
        spmm_kernel<<<2048, 256, 0, stream>>>(xc, x0, dinv, rs, scol, hb, N_NODES);
        dense_stats_kernel<<<1024, 256, 0, stream>>>(hb,
                cw + (size_t)i * HID * HID, stats + i * 128, beta, N_NODES);
        layerB_kernel<<<(N_NODES * HID / 4 + 255) / 256, 256, 0, stream>>>(
                (float4*)hb, (const float4*)xc,
                stats + i * 128, gamma + i * HID, bnb + i * HID, N_NODES * HID / 4);
        xc = hb;
    }
    final_kernel<<<2048, 256, 0, stream>>>(xc, W1, b1, out, N_NODES);
}

// Round 5
// 952.426 us; speedup vs baseline: 2.1523x; 1.0377x over previous
//
#include <hip/hip_runtime.h>
#include <math.h>

#define N_NODES 100000
#define N_EDGES 1000000
#define IN_F 128
#define HID 64
#define OUT_F 64
#define NLAYERS 4
#define ALPHA 0.1f
#define BN_EPS 1e-5f

#define SCAN_BLK 256
#define NSCAN_BLOCKS ((N_NODES + SCAN_BLK - 1) / SCAN_BLK)   // 391

// ---- workspace layout (bytes) ----
// Feature buffers first: fp32 rows 256B-aligned, bf16 gather rows 128B-aligned.
static const size_t OFF_X0       = 0;                       // N*64*4 = 25600000
static const size_t OFF_HA       = 25600000;
static const size_t OFF_HB       = 51200000;
static const size_t OFF_GB       = 76800000;                // N*64*2 = 12800000 (bf16, dinv-prescaled)
static const size_t OFF_SORTED   = 89600000;                // E*4 = 4000000
static const size_t OFF_CNT      = 93600000;                // N*4
static const size_t OFF_STATS    = 94000000;                // 512*4 = 2048
static const size_t OFF_DINV     = 94002048;                // N*4
static const size_t OFF_ROWSTART = 94402048;                // (N+1)*4 -> 400016
static const size_t OFF_CURSOR   = 94802064;                // N*4
static const size_t OFF_BSUM     = 95202064;                // 391*4 -> pad 2048; end = 95204112
static const size_t ZERO_OFF     = OFF_CNT;                 // cnt+stats contiguous
static const size_t ZERO_BYTES   = 402048;

__device__ __forceinline__ unsigned short f2b(float f) {
    unsigned int u = __float_as_uint(f);
    u += 0x7FFFu + ((u >> 16) & 1u);        // round-to-nearest-even
    return (unsigned short)(u >> 16);
}
__device__ __forceinline__ float b2f(unsigned short h) {
    return __uint_as_float(((unsigned int)h) << 16);
}

__global__ void hist_kernel(const int* __restrict__ row, int* __restrict__ cnt, int e) {
    int i = blockIdx.x * blockDim.x + threadIdx.x;
    if (i < e) atomicAdd(&cnt[row[i]], 1);
}

__global__ void dinv_kernel(const int* __restrict__ cnt, float* __restrict__ dinv, int n) {
    int i = blockIdx.x * blockDim.x + threadIdx.x;
    if (i < n) {
        int d = cnt[i];
        dinv[i] = d > 0 ? rsqrtf((float)d) : 0.0f;
    }
}

// ---- 3-phase multi-block exclusive scan of cnt -> rs[0..n], cur ----
__global__ __launch_bounds__(SCAN_BLK) void blocksum_kernel(const int* __restrict__ cnt,
        int* __restrict__ bsum, int n) {
    __shared__ int red[SCAN_BLK / 64];
    int i = blockIdx.x * SCAN_BLK + threadIdx.x;
    int v = (i < n) ? cnt[i] : 0;
#pragma unroll
    for (int off = 32; off > 0; off >>= 1) v += __shfl_down(v, off, 64);
    if ((threadIdx.x & 63) == 0) red[threadIdx.x >> 6] = v;
    __syncthreads();
    if (threadIdx.x == 0) {
        int s = 0;
#pragma unroll
        for (int j = 0; j < SCAN_BLK / 64; ++j) s += red[j];
        bsum[blockIdx.x] = s;
    }
}

__global__ __launch_bounds__(512) void scan_bsum_kernel(int* __restrict__ bsum, int nb) {
    __shared__ int lds[512];
    int t = threadIdx.x;
    lds[t] = (t < nb) ? bsum[t] : 0;
    __syncthreads();
    for (int off = 1; off < 512; off <<= 1) {
        int v = lds[t];
        int add = (t >= off) ? lds[t - off] : 0;
        __syncthreads();
        lds[t] = v + add;
        __syncthreads();
    }
    if (t < nb) bsum[t] = (t == 0) ? 0 : lds[t - 1];
}

__global__ __launch_bounds__(SCAN_BLK) void scan_write_kernel(const int* __restrict__ cnt,
        const int* __restrict__ bsum, int* __restrict__ rs, int* __restrict__ cur, int n) {
    __shared__ int lds[SCAN_BLK];
    int t = threadIdx.x;
    int i = blockIdx.x * SCAN_BLK + t;
    int c = (i < n) ? cnt[i] : 0;
    lds[t] = c;
    __syncthreads();
    for (int off = 1; off < SCAN_BLK; off <<= 1) {
        int v = lds[t];
        int add = (t >= off) ? lds[t - off] : 0;
        __syncthreads();
        lds[t] = v + add;
        __syncthreads();
    }
    if (i < n) {
        int excl = bsum[blockIdx.x] + lds[t] - c;
        rs[i] = excl;
        cur[i] = excl;
        if (i == n - 1) rs[n] = excl + c;
    }
}

__global__ void scatter_kernel(const int* __restrict__ edges, int* __restrict__ cur,
                               int* __restrict__ scol, int e) {
    int i = blockIdx.x * blockDim.x + threadIdx.x;
    if (i < e) {
        int r = edges[i];
        int c = edges[e + i];
        int pos = atomicAdd(&cur[r], 1);
        scol[pos] = c;
    }
}

// x0 = relu(x @ W0 + b0); also writes g = bf16(dinv[r]*x0) gather twin.
// (256,1): allow ~160 VGPR so the 128-entry weight array never spills.
__global__ __launch_bounds__(256, 1) void fc0_kernel(const float* __restrict__ x,
        const float* __restrict__ W0, const float* __restrict__ b0,
        const float* __restrict__ dinv, float* __restrict__ out,
        unsigned short* __restrict__ g, int n) {
    int wave = threadIdx.x >> 6, lane = threadIdx.x & 63;
    float w[IN_F];
#pragma unroll
    for (int k = 0; k < IN_F; ++k) w[k] = W0[k * HID + lane];
    float bias = b0[lane];
    int nw = gridDim.x * 4;
    for (int r = blockIdx.x * 4 + wave; r < n; r += nw) {
        float xa = x[(size_t)r * IN_F + lane];
        float xb = x[(size_t)r * IN_F + 64 + lane];
        float acc0 = bias, acc1 = 0.f;
#pragma unroll
        for (int k = 0; k < 64; ++k) {
            acc0 += __shfl(xa, k, 64) * w[k];
            acc1 += __shfl(xb, k, 64) * w[64 + k];
        }
        float v = acc0 + acc1;
        v = v > 0.f ? v : 0.f;
        out[(size_t)r * HID + lane] = v;
        g[(size_t)r * HID + lane] = f2b(dinv[r] * v);
    }
}

// SPMM from bf16 dinv-prescaled gather buffer: one 128B line per edge,
// no per-edge dinv load. Predicated batch-8 for MLP (lean regs, no spill).
__global__ __launch_bounds__(256, 8) void spmm_kernel(const unsigned short* __restrict__ g,
        const float* __restrict__ x0, const float* __restrict__ dinv,
        const int* __restrict__ rs, const int* __restrict__ scol,
        float* __restrict__ sout, int n) {
    int wave = threadIdx.x >> 6, lane = threadIdx.x & 63;
    int nw = gridDim.x * 4;
    for (int r = blockIdx.x * 4 + wave; r < n; r += nw) {
        int e0 = rs[r], e1 = rs[r + 1];
        float agg = 0.f;
        for (int e = e0; e < e1; e += 8) {
            int cc[8];
            float vv[8];
#pragma unroll
            for (int j = 0; j < 8; ++j) {
                int ee = e + j;
                cc[j] = scol[ee < e1 ? ee : e1 - 1];
            }
#pragma unroll
            for (int j = 0; j < 8; ++j) {
                float v = b2f(g[(size_t)cc[j] * HID + lane]);
                vv[j] = (e + j < e1) ? v : 0.f;
            }
            agg += ((vv[0] + vv[1]) + (vv[2] + vv[3])) +
                   ((vv[4] + vv[5]) + (vv[6] + vv[7]));
        }
        sout[(size_t)r * HID + lane] =
            (1.f - ALPHA) * dinv[r] * agg + ALPHA * x0[(size_t)r * HID + lane];
    }
}

// h = (1-beta)*s + beta*(s@cw), in place; per-channel sum/sumsq block-reduced.
__global__ __launch_bounds__(256, 2) void dense_stats_kernel(float* __restrict__ s_in,
        const float* __restrict__ cw, float* __restrict__ stats, float beta, int n) {
    __shared__ float red[4 * 128];
    int wave = threadIdx.x >> 6, lane = threadIdx.x & 63;
    float w[HID];
#pragma unroll
    for (int k = 0; k < HID; ++k) w[k] = cw[k * HID + lane];
    float lsum = 0.f, lsq = 0.f;
    int nw = gridDim.x * 4;
    for (int r = blockIdx.x * 4 + wave; r < n; r += nw) {
        float sv = s_in[(size_t)r * HID + lane];
        float m = 0.f;
#pragma unroll
        for (int k = 0; k < HID; ++k) m += __shfl(sv, k, 64) * w[k];
        float hv = (1.f - beta) * sv + beta * m;
        s_in[(size_t)r * HID + lane] = hv;
        lsum += hv; lsq += hv * hv;
    }
    red[wave * 128 + lane] = lsum;
    red[wave * 128 + 64 + lane] = lsq;
    __syncthreads();
    if (threadIdx.x < 128) {
        int t = threadIdx.x;
        float v = red[t] + red[128 + t] + red[256 + t] + red[384 + t];
        atomicAdd(&stats[t], v);
    }
}

// BN + residual + relu in place; also writes next-layer gather twin g = bf16(dinv*out)
__global__ void layerB_kernel(float4* __restrict__ h, const float4* __restrict__ xprev,
        const float* __restrict__ stats, const float* __restrict__ gamma,
        const float* __restrict__ bnb, const float* __restrict__ dinv,
        ushort4* __restrict__ g, int total4) {
    int i = blockIdx.x * blockDim.x + threadIdx.x;
    if (i >= total4) return;
    int fb = (i & 15) * 4;
    int row = i >> 4;
    float dr = dinv[row];
    float4 hv = h[i];
    float4 xp = xprev[i];
    float o[4];
    float hin[4] = { hv.x, hv.y, hv.z, hv.w };
    float xin[4] = { xp.x, xp.y, xp.z, xp.w };
#pragma unroll
    for (int j = 0; j < 4; ++j) {
        int f = fb + j;
        float mu = stats[f] * (1.0f / N_NODES);
        float var = stats[64 + f] * (1.0f / N_NODES) - mu * mu;
        if (var < 0.f) var = 0.f;
        float inv = rsqrtf(var + BN_EPS);
        float v = (hin[j] - mu) * inv * gamma[f] + bnb[f] + xin[j];
        o[j] = v > 0.f ? v : 0.f;
    }
    h[i] = make_float4(o[0], o[1], o[2], o[3]);
    ushort4 gu;
    gu.x = f2b(dr * o[0]); gu.y = f2b(dr * o[1]);
    gu.z = f2b(dr * o[2]); gu.w = f2b(dr * o[3]);
    g[i] = gu;
}

// out = x @ W1 + b1
__global__ __launch_bounds__(256, 2) void final_kernel(const float* __restrict__ xcur,
        const float* __restrict__ W1, const float* __restrict__ b1,
        float* __restrict__ out, int n) {
    int wave = threadIdx.x >> 6, lane = threadIdx.x & 63;
    float w[HID];
#pragma unroll
    for (int k = 0; k < HID; ++k) w[k] = W1[k * OUT_F + lane];
    float bias = b1[lane];
    int nw = gridDim.x * 4;
    for (int r = blockIdx.x * 4 + wave; r < n; r += nw) {
        float xv = xcur[(size_t)r * HID + lane];
        float acc = bias;
#pragma unroll
        for (int k = 0; k < HID; ++k) acc += __shfl(xv, k, 64) * w[k];
        out[(size_t)r * OUT_F + lane] = acc;
    }
}

extern "C" void kernel_launch(void* const* d_in, const int* in_sizes, int n_in,
                              void* d_out, int out_size, void* d_ws, size_t ws_size,
                              hipStream_t stream) {
    const float* x     = (const float*)d_in[0];
    const int*   edges = (const int*)d_in[1];
    const float* W0    = (const float*)d_in[2];
    const float* b0    = (const float*)d_in[3];
    const float* cw    = (const float*)d_in[4];
    const float* gamma = (const float*)d_in[5];
    const float* bnb   = (const float*)d_in[6];
    const float* W1    = (const float*)d_in[7];
    const float* b1    = (const float*)d_in[8];
    float* out = (float*)d_out;

    char* ws = (char*)d_ws;
    float* x0    = (float*)(ws + OFF_X0);
    float* bufA  = (float*)(ws + OFF_HA);
    float* bufB  = (float*)(ws + OFF_HB);
    unsigned short* gbuf = (unsigned short*)(ws + OFF_GB);
    int*   scol  = (int*)(ws + OFF_SORTED);
    int*   cnt   = (int*)(ws + OFF_CNT);
    float* stats = (float*)(ws + OFF_STATS);
    float* dinv  = (float*)(ws + OFF_DINV);
    int*   rs    = (int*)(ws + OFF_ROWSTART);
    int*   cur   = (int*)(ws + OFF_CURSOR);
    int*   bsum  = (int*)(ws + OFF_BSUM);

    hipMemsetAsync(ws + ZERO_OFF, 0, ZERO_BYTES, stream);
    hist_kernel<<<(N_EDGES + 255) / 256, 256, 0, stream>>>(edges, cnt, N_EDGES);
    dinv_kernel<<<(N_NODES + 255) / 256, 256, 0, stream>>>(cnt, dinv, N_NODES);
    blocksum_kernel<<<NSCAN_BLOCKS, SCAN_BLK, 0, stream>>>(cnt, bsum, N_NODES);
    scan_bsum_kernel<<<1, 512, 0, stream>>>(bsum, NSCAN_BLOCKS);
    scan_write_kernel<<<NSCAN_BLOCKS, SCAN_BLK, 0, stream>>>(cnt, bsum, rs, cur, N_NODES);
    scatter_kernel<<<(N_EDGES + 255) / 256, 256, 0, stream>>>(edges, cur, scol, N_EDGES);
    fc0_kernel<<<2048, 256, 0, stream>>>(x, W0, b0, dinv, x0, gbuf, N_NODES);

    const float* xc = x0;
    float* bufs[2] = { bufA, bufB };
    for (int i = 0; i < NLAYERS; ++i) {
        float beta = logf(0.5f / (float)(i + 1) + 1.0f);
        float* hb = bufs[i & 1];
        spmm_kernel<<<2048, 256, 0, stream>>>(gbuf, x0, dinv, rs, scol, hb, N_NODES);
        dense_stats_kernel<<<1024, 256, 0, stream>>>(hb,
                cw + (size_t)i * HID * HID, stats + i * 128, beta, N_NODES);
        layerB_kernel<<<(N_NODES * HID / 4 + 255) / 256, 256, 0, stream>>>(
                (float4*)hb, (const float4*)xc,
                stats + i * 128, gamma + i * HID, bnb + i * HID, dinv,
                (ushort4*)gbuf, N_NODES * HID / 4);
        xc = hb;
    }
    final_kernel<<<2048, 256, 0, stream>>>(xc, W1, b1, out, N_NODES);
}